// Round 9
// baseline (458.298 us; speedup 1.0000x reference)
//
#include <hip/hip_runtime.h>

#define NN 50000
#define EE 800000
#define BB 1000
#define NB 196      // scan blocks (barrier participants)
#define NR 5        // node ranges for LDS histogram
#define RS 10496    // range size, NR*RS = 52480 >= NN
#define NC 32       // edge chunks / partial copies
#define CHUNK 25000 // EE/NC

#define BUILD2 31250  // NN*160/256
#define PACK2 408     // (15*12*512 + 6*4*512)/256
#define FINBLKS 782   // ceil(3125 waves / 4)

typedef unsigned short u16;
typedef __attribute__((ext_vector_type(8))) short bf16x8;
typedef __attribute__((ext_vector_type(4))) float f32x4;

static __device__ __forceinline__ u16 f2b(float f) {
    union { float f; unsigned u; } v;
    v.f = f;
    unsigned r = v.u + 0x7fffu + ((v.u >> 16) & 1u);
    return (u16)(r >> 16);
}

static __device__ __forceinline__ float b2f(short s) {
    union { unsigned u; float f; } c;
    c.u = ((unsigned)(u16)s) << 16;
    return c.f;
}

// ---------------- histogram: deg(src) f32 + cnt(dst) packed u16, LDS only ----------------
__global__ __launch_bounds__(512) void k_hist(
    const int* __restrict__ src, const int* __restrict__ dst,
    const float* __restrict__ ew, float* __restrict__ deg_p,
    int* __restrict__ cnt_p, int* __restrict__ ctr) {
    __shared__ float sdeg[RS];
    __shared__ unsigned scnt2[RS / 2];
    if (blockIdx.x == 0 && threadIdx.x == 0) atomicExch(ctr, 0);  // for k_scan barrier
    int r = blockIdx.x % NR;
    int c = blockIdx.x / NR;
    int base = r * RS;
    for (int i = threadIdx.x; i < RS; i += 512) sdeg[i] = 0.f;
    for (int i = threadIdx.x; i < RS / 2; i += 512) scnt2[i] = 0u;
    __syncthreads();
    int e0 = c * CHUNK;
    for (int j = threadIdx.x; j < CHUNK; j += 512) {
        int e = e0 + j;
        int s = src[e], d = dst[e];
        int sl = s - base, dl = d - base;
        if ((unsigned)sl < RS) atomicAdd(&sdeg[sl], ew[e]);
        if ((unsigned)dl < RS) atomicAdd(&scnt2[dl >> 1], (dl & 1) ? 65536u : 1u);
    }
    __syncthreads();
    int lim = (NN - base < RS) ? (NN - base) : RS;
    for (int i = threadIdx.x; i < lim; i += 512) {
        deg_p[(size_t)c * NN + base + i] = sdeg[i];
        cnt_p[(size_t)c * NN + base + i] = (int)((scnt2[i >> 1] >> ((i & 1) * 16)) & 0xffffu);
    }
}

// ---------------- fused scan (+grid barrier) | build A0 | pack weights ----------------
// A-level k-layout per level: [x-part(96) | h-part(64)]; levels in A0/A1/A2.
__global__ __launch_bounds__(256) void k_scan_build(
    const int* __restrict__ cnt_p, const float* __restrict__ deg_p,
    int* __restrict__ cnt, int* __restrict__ cbase, float* __restrict__ dinv,
    int* __restrict__ bsum, int* __restrict__ ctr,
    const float* __restrict__ z, const float* __restrict__ x,
    const float* __restrict__ ph, u16* __restrict__ A0,
    const float* __restrict__ Wxz, const float* __restrict__ Wxr,
    const float* __restrict__ Wxh, const float* __restrict__ Whz,
    const float* __restrict__ Whr, const float* __restrict__ Whh,
    u16* __restrict__ Wp, u16* __restrict__ W3p) {
    if (blockIdx.x >= NB) {
        int bid = blockIdx.x - NB;
        if (bid < BUILD2) {
            int i = bid * 256 + threadIdx.x;  // over NN*160 exactly
            int n = i / 160, c = i - n * 160;
            float v;
            if (c < 64) v = z[n * 64 + c];
            else if (c < 96) v = x[n * 32 + (c - 64)];
            else v = ph[n * 64 + (c - 96)];
            A0[(size_t)n * 160 + c] = f2b(v);
        } else {
            int idx = (bid - BUILD2) * 256 + threadIdx.x;
            if (idx < 15 * 12 * 512) {
                int j = idx & 7, l = (idx >> 3) & 63;
                int ct = (idx >> 9) % 12, s = (idx >> 9) / 12;
                int k = 32 * s + (l >> 4) * 8 + j;
                int g = ct >> 2;
                int c = 16 * (ct & 3) + (l & 15);
                int lvl = k / 160, kk = k - lvl * 160;
                float val;
                if (kk < 96) {
                    const float* W = (g == 0) ? Wxz : ((g == 1) ? Wxr : Wxh);
                    val = W[(lvl * 96 + kk) * 64 + c];
                } else if (g == 2) {
                    val = 0.f;
                } else {
                    const float* W = (g == 0) ? Whz : Whr;
                    val = W[(lvl * 64 + (kk - 96)) * 64 + c];
                }
                Wp[idx] = f2b(val);
            } else {
                int i2 = idx - 15 * 12 * 512;
                int j = i2 & 7, l = (i2 >> 3) & 63;
                int ct = (i2 >> 9) & 3, s = i2 >> 11;
                int k = 32 * s + (l >> 4) * 8 + j;
                int ki = k >> 6, kr = k & 63;
                int c = 16 * ct + (l & 15);
                W3p[i2] = f2b(Whh[(ki * 64 + kr) * 64 + c]);
            }
        }
        return;
    }
    __shared__ int s[256];
    int b = blockIdx.x;
    int i = b * 256 + threadIdx.x;
    int v = 0;
    float d = 0.f;
    if (i < NN) {
#pragma unroll
        for (int p = 0; p < NC; p++) v += cnt_p[(size_t)p * NN + i];
#pragma unroll
        for (int p = 0; p < NC; p++) d += deg_p[(size_t)p * NN + i];
        cnt[i] = v;
    }
    s[threadIdx.x] = v;
    __syncthreads();
    for (int off = 1; off < 256; off <<= 1) {
        int t = (threadIdx.x >= off) ? s[threadIdx.x - off] : 0;
        __syncthreads();
        s[threadIdx.x] += t;
        __syncthreads();
    }
    int incl = s[threadIdx.x];
    if (threadIdx.x == 255) atomicExch(&bsum[b], s[255]);
    __threadfence();
    if (threadIdx.x == 0) {
        atomicAdd(ctr, 1);
        while (atomicAdd(ctr, 0) < NB) __builtin_amdgcn_s_sleep(8);
    }
    __syncthreads();
    __threadfence();
    int pv = (threadIdx.x < b) ? atomicAdd(&bsum[threadIdx.x], 0) : 0;
    s[threadIdx.x] = pv;
    __syncthreads();
    for (int off = 128; off > 0; off >>= 1) {
        if (threadIdx.x < off) s[threadIdx.x] += s[threadIdx.x + off];
        __syncthreads();
    }
    int prefix = s[0];
    if (i < NN) {
        int run = prefix + incl - v;  // row_ptr[i]
        dinv[i] = d > 0.f ? rsqrtf(d) : 0.f;
#pragma unroll
        for (int c = 0; c < NC; c++) {
            cbase[(size_t)c * NN + i] = run;
            run += cnt_p[(size_t)c * NN + i];
        }
    }
}

// ---------------- scatter with LDS ranks: zero global atomics ----------------
__global__ __launch_bounds__(512) void k_scatter_rank(
    const int* __restrict__ src, const int* __restrict__ dst,
    const float* __restrict__ ew, const float* __restrict__ dinv,
    const int* __restrict__ cbase, uint2* __restrict__ csr8) {
    __shared__ unsigned rank2[RS / 2];
    int r = blockIdx.x % NR;
    int c = blockIdx.x / NR;
    int base = r * RS;
    for (int i = threadIdx.x; i < RS / 2; i += 512) rank2[i] = 0u;
    __syncthreads();
    int e0 = c * CHUNK;
    for (int j = threadIdx.x; j < CHUNK; j += 512) {
        int e = e0 + j;
        int d = dst[e];
        int dl = d - base;
        if ((unsigned)dl < RS) {
            int s = src[e];
            unsigned old = atomicAdd(&rank2[dl >> 1], (dl & 1) ? 65536u : 1u);
            int rank = (int)((old >> ((dl & 1) * 16)) & 0xffffu);
            int pos = cbase[(size_t)c * NN + d] + rank;
            float w = dinv[s] * ew[e] * dinv[d];
            csr8[pos] = make_uint2((unsigned)s, __float_as_uint(w));
        }
    }
}

// ---------------- bf16 pull propagation, 16 ch/thread, separate in/base/out ----------------
template <int C, int SCALE, bool HB, int BS, int INS, int OUTS>
__global__ __launch_bounds__(BS) void k_pull(
    const u16* __restrict__ in, const u16* __restrict__ base, u16* __restrict__ out,
    const uint2* __restrict__ csr8, const int* __restrict__ row_ptr,
    const int* __restrict__ cnt) {
    constexpr int TPR = C / 16;
    int tid = blockIdx.x * BS + threadIdx.x;
    int r = tid / TPR;
    int c16 = (tid - r * TPR) * 16;
    if (r >= NN) return;
    int s0 = row_ptr[r], n = cnt[r];
    float acc[16];
#pragma unroll
    for (int k = 0; k < 16; k++) acc[k] = 0.f;
    const u16* inp = in + c16;
    uint2 e = (n > 0) ? csr8[s0] : make_uint2(0u, 0u);
    for (int j = 0; j < n; j++) {
        uint2 ec = e;
        if (j + 1 < n) e = csr8[s0 + j + 1];
        float w = __uint_as_float(ec.y);
        const u16* p = inp + (size_t)ec.x * INS;
        bf16x8 v0 = *(const bf16x8*)(p);
        bf16x8 v1 = *(const bf16x8*)(p + 8);
#pragma unroll
        for (int k = 0; k < 8; k++) {
            acc[k] += w * b2f(v0[k]);
            acc[8 + k] += w * b2f(v1[k]);
        }
    }
    const float sc = -(float)SCALE;
    float o[16];
    if (HB) {
        const u16* bp = base + (size_t)r * INS + c16;
        bf16x8 b0 = *(const bf16x8*)(bp);
        bf16x8 b1 = *(const bf16x8*)(bp + 8);
#pragma unroll
        for (int k = 0; k < 8; k++) {
            o[k] = sc * acc[k] - b2f(b0[k]);
            o[8 + k] = sc * acc[8 + k] - b2f(b1[k]);
        }
    } else {
#pragma unroll
        for (int k = 0; k < 16; k++) o[k] = sc * acc[k];
    }
    bf16x8 p0, p1;
#pragma unroll
    for (int k = 0; k < 8; k++) {
        p0[k] = (short)f2b(o[k]);
        p1[k] = (short)f2b(o[8 + k]);
    }
    u16* op = out + (size_t)r * OUTS + c16;
    *(bf16x8*)(op) = p0;
    *(bf16x8*)(op + 8) = p1;
}

// ---------------- gates GEMM (MFMA): A0|A1|A2 x Wp[480,192] -> Zb16, Hx16, A3 ----------------
__global__ __launch_bounds__(256) void k_gates_mfma(
    const u16* __restrict__ A0, const u16* __restrict__ A1, const u16* __restrict__ A2,
    const u16* __restrict__ Wp,
    const float* __restrict__ bxz, const float* __restrict__ bhz,
    const float* __restrict__ bxr, const float* __restrict__ bhr,
    const float* __restrict__ bxh,
    u16* __restrict__ Zb16, u16* __restrict__ Hx16, u16* __restrict__ A3) {
    int wv = (blockIdx.x * 256 + threadIdx.x) >> 6;
    int lane = threadIdx.x & 63;
    int r0 = wv * 16;
    if (r0 >= NN) return;
    int q = lane >> 4, j0 = lane & 15;

    f32x4 acc[12];
#pragma unroll
    for (int i = 0; i < 12; i++) acc[i] = (f32x4){0.f, 0.f, 0.f, 0.f};

    size_t rofs = (size_t)(r0 + j0) * 160 + q * 8;
    const u16* arow[3] = {A0 + rofs, A1 + rofs, A2 + rofs};
#pragma unroll
    for (int s = 0; s < 15; s++) {
        bf16x8 a = *(const bf16x8*)(arow[s / 5] + 32 * (s % 5));
        const u16* bp = Wp + (size_t)(s * 12) * 512 + lane * 8;
#pragma unroll
        for (int ct = 0; ct < 12; ct++) {
            bf16x8 b = *(const bf16x8*)(bp + ct * 512);
            acc[ct] = __builtin_amdgcn_mfma_f32_16x16x32_bf16(a, b, acc[ct], 0, 0, 0);
        }
    }

#pragma unroll
    for (int ct = 0; ct < 4; ct++) {
        int j = 16 * ct + j0;
        float bz = bxz[j] + bhz[j];
        float br = bxr[j] + bhr[j];
        float bh = bxh[j];
#pragma unroll
        for (int reg = 0; reg < 4; reg++) {
            int r = r0 + q * 4 + reg;
            size_t i = (size_t)r * 64 + j;
            float zp = acc[ct][reg] + bz;
            float rp = acc[ct + 4][reg] + br;
            float hp = acc[ct + 8][reg] + bh;
            float zv = 1.f / (1.f + expf(-zp));
            float rv = 1.f / (1.f + expf(-rp));
            float phv = b2f((short)A0[(size_t)r * 160 + 96 + j]);
            Zb16[i] = f2b(zv);
            Hx16[i] = f2b(hp);
            A3[(size_t)r * 192 + j] = f2b(rv * phv);
        }
    }
}

// ---------------- final GEMM + GRU blend, fused with batch tail ----------------
__global__ __launch_bounds__(256) void k_final_tail(
    const u16* __restrict__ A3, const u16* __restrict__ W3p,
    const float* __restrict__ bhh, const u16* __restrict__ Hx16,
    const u16* __restrict__ Zb16, const u16* __restrict__ A0,
    float* __restrict__ outh,
    const float* __restrict__ z, const int* __restrict__ batch,
    const float* __restrict__ u, const float* __restrict__ Wg,
    const float* __restrict__ bg, float* __restrict__ outF) {
    if (blockIdx.x >= FINBLKS) {
        int b = ((blockIdx.x - FINBLKS) * 256 + threadIdx.x) >> 6;
        int lane = threadIdx.x & 63;
        if (b >= BB) return;
        int lo = 0, hi = NN;
        while (lo < hi) {
            int m = (lo + hi) >> 1;
            if (batch[m] < b) lo = m + 1; else hi = m;
        }
        int start = lo;
        hi = NN;
        while (lo < hi) {
            int m = (lo + hi) >> 1;
            if (batch[m] < b + 1) lo = m + 1; else hi = m;
        }
        int end = lo;
        float acc = 0.f;
        for (int n = start; n < end; n++) acc += z[(size_t)n * 64 + lane];
        float g = bg[lane];
        const float* ur = u + (size_t)b * 64;
        for (int k = 0; k < 64; k++) g += ur[k] * Wg[k * 64 + lane];
        g = fmaxf(g, 0.f);
        outF[(size_t)b * 128 + lane] = acc;
        outF[(size_t)b * 128 + 64 + lane] = g;
        return;
    }
    int wv = (blockIdx.x * 256 + threadIdx.x) >> 6;
    int lane = threadIdx.x & 63;
    int r0 = wv * 16;
    if (r0 >= NN) return;
    int q = lane >> 4, j0 = lane & 15;

    f32x4 acc[4];
#pragma unroll
    for (int i = 0; i < 4; i++) acc[i] = (f32x4){0.f, 0.f, 0.f, 0.f};

    const u16* arow = A3 + (size_t)(r0 + j0) * 192 + q * 8;
#pragma unroll
    for (int s = 0; s < 6; s++) {
        bf16x8 a = *(const bf16x8*)(arow + 32 * s);
        const u16* bp = W3p + (size_t)(s * 4) * 512 + lane * 8;
#pragma unroll
        for (int ct = 0; ct < 4; ct++) {
            bf16x8 b = *(const bf16x8*)(bp + ct * 512);
            acc[ct] = __builtin_amdgcn_mfma_f32_16x16x32_bf16(a, b, acc[ct], 0, 0, 0);
        }
    }

#pragma unroll
    for (int ct = 0; ct < 4; ct++) {
        int j = 16 * ct + j0;
        float bh = bhh[j];
#pragma unroll
        for (int reg = 0; reg < 4; reg++) {
            int r = r0 + q * 4 + reg;
            size_t i = (size_t)r * 64 + j;
            float ht = tanhf(b2f((short)Hx16[i]) + acc[ct][reg] + bh);
            float zv = b2f((short)Zb16[i]);
            float phv = b2f((short)A0[(size_t)r * 160 + 96 + j]);
            outh[i] = zv * phv + (1.f - zv) * ht;
        }
    }
}

extern "C" void kernel_launch(void* const* d_in, const int* in_sizes, int n_in,
                              void* d_out, int out_size, void* d_ws, size_t ws_size,
                              hipStream_t stream) {
    const float* x  = (const float*)d_in[0];
    const float* u  = (const float*)d_in[1];
    const float* z  = (const float*)d_in[2];
    const int*   ei = (const int*)d_in[3];
    const float* ew = (const float*)d_in[4];
    const int* batch = (const int*)d_in[5];
    const float* ph = (const float*)d_in[7];
    const float *Wxz = (const float*)d_in[8],  *bxz = (const float*)d_in[9];
    const float *Whz = (const float*)d_in[10], *bhz = (const float*)d_in[11];
    const float *Wxr = (const float*)d_in[12], *bxr = (const float*)d_in[13];
    const float *Whr = (const float*)d_in[14], *bhr = (const float*)d_in[15];
    const float *Wxh = (const float*)d_in[16], *bxh = (const float*)d_in[17];
    const float *Whh = (const float*)d_in[18], *bhh = (const float*)d_in[19];
    const float *Wg  = (const float*)d_in[20], *bg  = (const float*)d_in[21];
    const int* src = ei;
    const int* dst = ei + EE;

    char* wsb = (char*)d_ws;
    size_t o = 0;
    auto alloc = [&](size_t bytes) {
        void* p = wsb + o;
        o += (bytes + 255) & ~(size_t)255;
        return p;
    };
    float* deg_p = (float*)alloc((size_t)NC * NN * 4);  // fully overwritten
    int*   cnt_p = (int*)alloc((size_t)NC * NN * 4);    // fully overwritten
    int*   cnt   = (int*)alloc(NN * 4);
    int*   cbase = (int*)alloc((size_t)NC * NN * 4);    // cbase[0..NN) == row_ptr
    float* dinv  = (float*)alloc(NN * 4);
    int*   bsum  = (int*)alloc(256 * 4);
    int*   ctr   = (int*)alloc(256);
    uint2* csr8  = (uint2*)alloc((size_t)EE * 8);
    u16*   Zb16  = (u16*)alloc((size_t)NN * 64 * 2);
    u16*   Hx16  = (u16*)alloc((size_t)NN * 64 * 2);
    u16*   A0    = (u16*)alloc((size_t)NN * 160 * 2);
    u16*   A1    = (u16*)alloc((size_t)NN * 160 * 2);
    u16*   A2    = (u16*)alloc((size_t)NN * 160 * 2);
    u16*   A3    = (u16*)alloc((size_t)NN * 192 * 2);
    u16*   Wp    = (u16*)alloc(15 * 12 * 512 * 2);
    u16*   W3p   = (u16*)alloc(6 * 4 * 512 * 2);

    float* outF = (float*)d_out;               // [B,128]
    float* outH = outF + (size_t)BB * 128;     // [N,64]

    const int BLK = 256;
    const int gPull160 = (NN + 31) / 32;  // 320 thr, 10 thr/row -> 32 rows/blk
    const int gPull64 = (NN + 63) / 64;   // 256 thr, 4 thr/row -> 64 rows/blk
    const int gTail = (BB * 64 + BLK - 1) / BLK;  // 250
    int* row_ptr = cbase;  // chunk-0 bases == row starts

    // 1. histograms (LDS-only atomics), resets barrier ctr
    k_hist<<<NR * NC, 512, 0, stream>>>(src, dst, ew, deg_p, cnt_p, ctr);

    // 2. fused scan (grid barrier -> row_ptr/cbase/dinv) | build A0 | pack weights
    k_scan_build<<<NB + BUILD2 + PACK2, 256, 0, stream>>>(
        cnt_p, deg_p, cnt, cbase, dinv, bsum, ctr,
        z, x, ph, A0, Wxz, Wxr, Wxh, Whz, Whr, Whh, Wp, W3p);

    // 3. scatter CSR records via LDS ranks (no global atomics)
    k_scatter_rank<<<NR * NC, 512, 0, stream>>>(src, dst, ew, dinv, cbase, csr8);

    // 4. Chebyshev bases: t1 = -prop(t0); t2 = -2*prop(t1) - t0
    k_pull<160, 1, false, 320, 160, 160><<<gPull160, 320, 0, stream>>>(
        A0, nullptr, A1, csr8, row_ptr, cnt);
    k_pull<160, 2, true, 320, 160, 160><<<gPull160, 320, 0, stream>>>(
        A1, A0, A2, csr8, row_ptr, cnt);

    // 5. gates GEMM -> Zb16, Hx16, A3 slice 0 (hr)
    k_gates_mfma<<<FINBLKS, BLK, 0, stream>>>(A0, A1, A2, Wp, bxz, bhz, bxr, bhr, bxh,
                                              Zb16, Hx16, A3);

    // 6. Chebyshev basis for hr (within A3, stride 192; 128B-aligned slices)
    k_pull<64, 1, false, 256, 192, 192><<<gPull64, 256, 0, stream>>>(
        A3, nullptr, A3 + 64, csr8, row_ptr, cnt);
    k_pull<64, 2, true, 256, 192, 192><<<gPull64, 256, 0, stream>>>(
        A3 + 64, A3, A3 + 128, csr8, row_ptr, cnt);

    // 7. candidate GEMM + GRU blend -> h out; extra blocks do batch tail -> fused out
    k_final_tail<<<FINBLKS + gTail, BLK, 0, stream>>>(A3, W3p, bhh, Hx16, Zb16, A0, outH,
                                                      z, batch, u, Wg, bg, outF);
}

// Round 10
// 449.260 us; speedup vs baseline: 1.0201x; 1.0201x over previous
//
#include <hip/hip_runtime.h>

#define NN 50000
#define EE 800000
#define BB 1000
#define NB 196      // scan blocks (barrier participants)
#define NR 5        // node ranges for LDS histogram
#define RS 10496    // range size, NR*RS = 52480 >= NN
#define NC 32       // edge chunks / partial copies
#define CHUNK 25000 // EE/NC

#define BUILDBLKS 15625  // NN*160/512
#define PACKBLKS 204     // (15*12*512 + 6*4*512)/512
#define FINBLKS 782      // ceil(3125 waves / 4)

typedef unsigned short u16;
typedef __attribute__((ext_vector_type(8))) short bf16x8;
typedef __attribute__((ext_vector_type(4))) float f32x4;

static __device__ __forceinline__ u16 f2b(float f) {
    union { float f; unsigned u; } v;
    v.f = f;
    unsigned r = v.u + 0x7fffu + ((v.u >> 16) & 1u);
    return (u16)(r >> 16);
}

static __device__ __forceinline__ float b2f(short s) {
    union { unsigned u; float f; } c;
    c.u = ((unsigned)(u16)s) << 16;
    return c.f;
}

// ---------------- histogram: deg(src) f32 + cnt(dst) packed u16, LDS only ----------------
__global__ __launch_bounds__(512) void k_hist(
    const int* __restrict__ src, const int* __restrict__ dst,
    const float* __restrict__ ew, float* __restrict__ deg_p,
    int* __restrict__ cnt_p, int* __restrict__ ctr) {
    __shared__ float sdeg[RS];
    __shared__ unsigned scnt2[RS / 2];
    if (blockIdx.x == 0 && threadIdx.x == 0) atomicExch(ctr, 0);  // for k_scan barrier
    int r = blockIdx.x % NR;
    int c = blockIdx.x / NR;
    int base = r * RS;
    for (int i = threadIdx.x; i < RS; i += 512) sdeg[i] = 0.f;
    for (int i = threadIdx.x; i < RS / 2; i += 512) scnt2[i] = 0u;
    __syncthreads();
    int e0 = c * CHUNK;
    for (int j = threadIdx.x; j < CHUNK; j += 512) {
        int e = e0 + j;
        int s = src[e], d = dst[e];
        int sl = s - base, dl = d - base;
        if ((unsigned)sl < RS) atomicAdd(&sdeg[sl], ew[e]);
        if ((unsigned)dl < RS) atomicAdd(&scnt2[dl >> 1], (dl & 1) ? 65536u : 1u);
    }
    __syncthreads();
    int lim = (NN - base < RS) ? (NN - base) : RS;
    for (int i = threadIdx.x; i < lim; i += 512) {
        deg_p[(size_t)c * NN + base + i] = sdeg[i];
        cnt_p[(size_t)c * NN + base + i] = (int)((scnt2[i >> 1] >> ((i & 1) * 16)) & 0xffffu);
    }
}

// ---------------- build A0 + pack weights (with Chebyshev folding) ----------------
// A-level k-layout per level: [x-part(96) | h-part(64)]; levels in A0/A1/A2.
// Folding: lvl0 -> W0 - W2, lvl1 -> W1, lvl2 -> 2*W2 (pull-2 computes U2 = -S(T1)).
__global__ __launch_bounds__(512) void k_build(
    const float* __restrict__ z, const float* __restrict__ x,
    const float* __restrict__ ph, u16* __restrict__ A0,
    const float* __restrict__ Wxz, const float* __restrict__ Wxr,
    const float* __restrict__ Wxh, const float* __restrict__ Whz,
    const float* __restrict__ Whr, const float* __restrict__ Whh,
    u16* __restrict__ Wp, u16* __restrict__ W3p) {
    int bid = blockIdx.x;
    if (bid < BUILDBLKS) {
        int i = bid * 512 + threadIdx.x;  // over NN*160 exactly
        int n = i / 160, c = i - n * 160;
        float v;
        if (c < 64) v = z[n * 64 + c];
        else if (c < 96) v = x[n * 32 + (c - 64)];
        else v = ph[n * 64 + (c - 96)];
        A0[(size_t)n * 160 + c] = f2b(v);
        return;
    }
    int idx = (bid - BUILDBLKS) * 512 + threadIdx.x;
    if (idx < 15 * 12 * 512) {
        int j = idx & 7, l = (idx >> 3) & 63;
        int ct = (idx >> 9) % 12, s = (idx >> 9) / 12;
        int k = 32 * s + (l >> 4) * 8 + j;
        int g = ct >> 2;
        int c = 16 * (ct & 3) + (l & 15);
        int lvl = k / 160, kk = k - lvl * 160;
        float val;
        if (kk < 96) {
            const float* W = (g == 0) ? Wxz : ((g == 1) ? Wxr : Wxh);
            if (lvl == 0)      val = W[kk * 64 + c] - W[(192 + kk) * 64 + c];
            else if (lvl == 1) val = W[(96 + kk) * 64 + c];
            else               val = 2.f * W[(192 + kk) * 64 + c];
        } else if (g == 2) {
            val = 0.f;
        } else {
            const float* W = (g == 0) ? Whz : Whr;
            int kh = kk - 96;
            if (lvl == 0)      val = W[kh * 64 + c] - W[(128 + kh) * 64 + c];
            else if (lvl == 1) val = W[(64 + kh) * 64 + c];
            else               val = 2.f * W[(128 + kh) * 64 + c];
        }
        Wp[idx] = f2b(val);
    } else {
        int i2 = idx - 15 * 12 * 512;
        int j = i2 & 7, l = (i2 >> 3) & 63;
        int ct = (i2 >> 9) & 3, s = i2 >> 11;
        int k = 32 * s + (l >> 4) * 8 + j;
        int ki = k >> 6, kr = k & 63;
        int c = 16 * ct + (l & 15);
        float val;
        if (ki == 0)      val = Whh[kr * 64 + c] - Whh[(128 + kr) * 64 + c];
        else if (ki == 1) val = Whh[(64 + kr) * 64 + c];
        else              val = 2.f * Whh[(128 + kr) * 64 + c];
        W3p[i2] = f2b(val);
    }
}

// ---------------- scan: reduce partials + prefix via grid barrier -> cbase/dinv ----------------
__global__ __launch_bounds__(256) void k_scan(
    const int* __restrict__ cnt_p, const float* __restrict__ deg_p,
    int* __restrict__ cnt, int* __restrict__ cbase, float* __restrict__ dinv,
    int* __restrict__ bsum, int* __restrict__ ctr) {
    __shared__ int s[256];
    int b = blockIdx.x;
    int i = b * 256 + threadIdx.x;
    int cp[NC];
    int v = 0;
    float d = 0.f;
    if (i < NN) {
#pragma unroll
        for (int p = 0; p < NC; p++) {
            cp[p] = cnt_p[(size_t)p * NN + i];
            v += cp[p];
            d += deg_p[(size_t)p * NN + i];
        }
        cnt[i] = v;
    }
    s[threadIdx.x] = v;
    __syncthreads();
    for (int off = 1; off < 256; off <<= 1) {
        int t = (threadIdx.x >= off) ? s[threadIdx.x - off] : 0;
        __syncthreads();
        s[threadIdx.x] += t;
        __syncthreads();
    }
    int incl = s[threadIdx.x];
    if (threadIdx.x == 255) atomicExch(&bsum[b], s[255]);
    __threadfence();
    if (threadIdx.x == 0) {
        atomicAdd(ctr, 1);
        while (atomicAdd(ctr, 0) < NB) __builtin_amdgcn_s_sleep(8);
    }
    __syncthreads();
    __threadfence();
    int pv = (threadIdx.x < b) ? atomicAdd(&bsum[threadIdx.x], 0) : 0;
    s[threadIdx.x] = pv;
    __syncthreads();
    for (int off = 128; off > 0; off >>= 1) {
        if (threadIdx.x < off) s[threadIdx.x] += s[threadIdx.x + off];
        __syncthreads();
    }
    int prefix = s[0];
    if (i < NN) {
        int run = prefix + incl - v;  // row_ptr[i]
        dinv[i] = d > 0.f ? rsqrtf(d) : 0.f;
#pragma unroll
        for (int c = 0; c < NC; c++) {
            cbase[(size_t)c * NN + i] = run;
            run += cp[c];
        }
    }
}

// ---------------- scatter with LDS ranks: zero global atomics ----------------
__global__ __launch_bounds__(512) void k_scatter_rank(
    const int* __restrict__ src, const int* __restrict__ dst,
    const float* __restrict__ ew, const float* __restrict__ dinv,
    const int* __restrict__ cbase, uint2* __restrict__ csr8) {
    __shared__ unsigned rank2[RS / 2];
    int r = blockIdx.x % NR;
    int c = blockIdx.x / NR;
    int base = r * RS;
    for (int i = threadIdx.x; i < RS / 2; i += 512) rank2[i] = 0u;
    __syncthreads();
    int e0 = c * CHUNK;
    for (int j = threadIdx.x; j < CHUNK; j += 512) {
        int e = e0 + j;
        int d = dst[e];
        int dl = d - base;
        if ((unsigned)dl < RS) {
            int s = src[e];
            unsigned old = atomicAdd(&rank2[dl >> 1], (dl & 1) ? 65536u : 1u);
            int rank = (int)((old >> ((dl & 1) * 16)) & 0xffffu);
            int pos = cbase[(size_t)c * NN + d] + rank;
            float w = dinv[s] * ew[e] * dinv[d];
            csr8[pos] = make_uint2((unsigned)s, __float_as_uint(w));
        }
    }
}

// ---------------- bf16 pull propagation: out[r] = -sum w*in[src], 16 ch/thread ----------------
template <int C, int BS, int INS, int OUTS>
__global__ __launch_bounds__(BS) void k_pull(
    const u16* __restrict__ in, u16* __restrict__ out,
    const uint2* __restrict__ csr8, const int* __restrict__ row_ptr,
    const int* __restrict__ cnt) {
    constexpr int TPR = C / 16;
    int tid = blockIdx.x * BS + threadIdx.x;
    int r = tid / TPR;
    int c16 = (tid - r * TPR) * 16;
    if (r >= NN) return;
    int s0 = row_ptr[r], n = cnt[r];
    float acc[16];
#pragma unroll
    for (int k = 0; k < 16; k++) acc[k] = 0.f;
    const u16* inp = in + c16;
    uint2 e = (n > 0) ? csr8[s0] : make_uint2(0u, 0u);
    for (int j = 0; j < n; j++) {
        uint2 ec = e;
        if (j + 1 < n) e = csr8[s0 + j + 1];
        float w = __uint_as_float(ec.y);
        const u16* p = inp + (size_t)ec.x * INS;
        bf16x8 v0 = *(const bf16x8*)(p);
        bf16x8 v1 = *(const bf16x8*)(p + 8);
#pragma unroll
        for (int k = 0; k < 8; k++) {
            acc[k] += w * b2f(v0[k]);
            acc[8 + k] += w * b2f(v1[k]);
        }
    }
    bf16x8 p0, p1;
#pragma unroll
    for (int k = 0; k < 8; k++) {
        p0[k] = (short)f2b(-acc[k]);
        p1[k] = (short)f2b(-acc[8 + k]);
    }
    u16* op = out + (size_t)r * OUTS + c16;
    *(bf16x8*)(op) = p0;
    *(bf16x8*)(op + 8) = p1;
}

// ---------------- gates GEMM (MFMA): A0|A1|A2 x Wp[480,192] -> Zb16, Hx16, A3 ----------------
__global__ __launch_bounds__(256) void k_gates_mfma(
    const u16* __restrict__ A0, const u16* __restrict__ A1, const u16* __restrict__ A2,
    const u16* __restrict__ Wp,
    const float* __restrict__ bxz, const float* __restrict__ bhz,
    const float* __restrict__ bxr, const float* __restrict__ bhr,
    const float* __restrict__ bxh,
    u16* __restrict__ Zb16, u16* __restrict__ Hx16, u16* __restrict__ A3) {
    int wv = (blockIdx.x * 256 + threadIdx.x) >> 6;
    int lane = threadIdx.x & 63;
    int r0 = wv * 16;
    if (r0 >= NN) return;
    int q = lane >> 4, j0 = lane & 15;

    f32x4 acc[12];
#pragma unroll
    for (int i = 0; i < 12; i++) acc[i] = (f32x4){0.f, 0.f, 0.f, 0.f};

    size_t rofs = (size_t)(r0 + j0) * 160 + q * 8;
    const u16* arow[3] = {A0 + rofs, A1 + rofs, A2 + rofs};
#pragma unroll
    for (int s = 0; s < 15; s++) {
        bf16x8 a = *(const bf16x8*)(arow[s / 5] + 32 * (s % 5));
        const u16* bp = Wp + (size_t)(s * 12) * 512 + lane * 8;
#pragma unroll
        for (int ct = 0; ct < 12; ct++) {
            bf16x8 b = *(const bf16x8*)(bp + ct * 512);
            acc[ct] = __builtin_amdgcn_mfma_f32_16x16x32_bf16(a, b, acc[ct], 0, 0, 0);
        }
    }

#pragma unroll
    for (int ct = 0; ct < 4; ct++) {
        int j = 16 * ct + j0;
        float bz = bxz[j] + bhz[j];
        float br = bxr[j] + bhr[j];
        float bh = bxh[j];
#pragma unroll
        for (int reg = 0; reg < 4; reg++) {
            int r = r0 + q * 4 + reg;
            size_t i = (size_t)r * 64 + j;
            float zp = acc[ct][reg] + bz;
            float rp = acc[ct + 4][reg] + br;
            float hp = acc[ct + 8][reg] + bh;
            float zv = 1.f / (1.f + expf(-zp));
            float rv = 1.f / (1.f + expf(-rp));
            float phv = b2f((short)A0[(size_t)r * 160 + 96 + j]);
            Zb16[i] = f2b(zv);
            Hx16[i] = f2b(hp);
            A3[(size_t)r * 192 + j] = f2b(rv * phv);
        }
    }
}

// ---------------- final GEMM + GRU blend, fused with batch tail ----------------
__global__ __launch_bounds__(256) void k_final_tail(
    const u16* __restrict__ A3, const u16* __restrict__ W3p,
    const float* __restrict__ bhh, const u16* __restrict__ Hx16,
    const u16* __restrict__ Zb16, const u16* __restrict__ A0,
    float* __restrict__ outh,
    const float* __restrict__ z, const int* __restrict__ batch,
    const float* __restrict__ u, const float* __restrict__ Wg,
    const float* __restrict__ bg, float* __restrict__ outF) {
    if (blockIdx.x >= FINBLKS) {
        int b = ((blockIdx.x - FINBLKS) * 256 + threadIdx.x) >> 6;
        int lane = threadIdx.x & 63;
        if (b >= BB) return;
        int lo = 0, hi = NN;
        while (lo < hi) {
            int m = (lo + hi) >> 1;
            if (batch[m] < b) lo = m + 1; else hi = m;
        }
        int start = lo;
        hi = NN;
        while (lo < hi) {
            int m = (lo + hi) >> 1;
            if (batch[m] < b + 1) lo = m + 1; else hi = m;
        }
        int end = lo;
        float acc = 0.f;
        for (int n = start; n < end; n++) acc += z[(size_t)n * 64 + lane];
        float g = bg[lane];
        const float* ur = u + (size_t)b * 64;
        for (int k = 0; k < 64; k++) g += ur[k] * Wg[k * 64 + lane];
        g = fmaxf(g, 0.f);
        outF[(size_t)b * 128 + lane] = acc;
        outF[(size_t)b * 128 + 64 + lane] = g;
        return;
    }
    int wv = (blockIdx.x * 256 + threadIdx.x) >> 6;
    int lane = threadIdx.x & 63;
    int r0 = wv * 16;
    if (r0 >= NN) return;
    int q = lane >> 4, j0 = lane & 15;

    f32x4 acc[4];
#pragma unroll
    for (int i = 0; i < 4; i++) acc[i] = (f32x4){0.f, 0.f, 0.f, 0.f};

    const u16* arow = A3 + (size_t)(r0 + j0) * 192 + q * 8;
#pragma unroll
    for (int s = 0; s < 6; s++) {
        bf16x8 a = *(const bf16x8*)(arow + 32 * s);
        const u16* bp = W3p + (size_t)(s * 4) * 512 + lane * 8;
#pragma unroll
        for (int ct = 0; ct < 4; ct++) {
            bf16x8 b = *(const bf16x8*)(bp + ct * 512);
            acc[ct] = __builtin_amdgcn_mfma_f32_16x16x32_bf16(a, b, acc[ct], 0, 0, 0);
        }
    }

#pragma unroll
    for (int ct = 0; ct < 4; ct++) {
        int j = 16 * ct + j0;
        float bh = bhh[j];
#pragma unroll
        for (int reg = 0; reg < 4; reg++) {
            int r = r0 + q * 4 + reg;
            size_t i = (size_t)r * 64 + j;
            float ht = tanhf(b2f((short)Hx16[i]) + acc[ct][reg] + bh);
            float zv = b2f((short)Zb16[i]);
            float phv = b2f((short)A0[(size_t)r * 160 + 96 + j]);
            outh[i] = zv * phv + (1.f - zv) * ht;
        }
    }
}

extern "C" void kernel_launch(void* const* d_in, const int* in_sizes, int n_in,
                              void* d_out, int out_size, void* d_ws, size_t ws_size,
                              hipStream_t stream) {
    const float* x  = (const float*)d_in[0];
    const float* u  = (const float*)d_in[1];
    const float* z  = (const float*)d_in[2];
    const int*   ei = (const int*)d_in[3];
    const float* ew = (const float*)d_in[4];
    const int* batch = (const int*)d_in[5];
    const float* ph = (const float*)d_in[7];
    const float *Wxz = (const float*)d_in[8],  *bxz = (const float*)d_in[9];
    const float *Whz = (const float*)d_in[10], *bhz = (const float*)d_in[11];
    const float *Wxr = (const float*)d_in[12], *bxr = (const float*)d_in[13];
    const float *Whr = (const float*)d_in[14], *bhr = (const float*)d_in[15];
    const float *Wxh = (const float*)d_in[16], *bxh = (const float*)d_in[17];
    const float *Whh = (const float*)d_in[18], *bhh = (const float*)d_in[19];
    const float *Wg  = (const float*)d_in[20], *bg  = (const float*)d_in[21];
    const int* src = ei;
    const int* dst = ei + EE;

    char* wsb = (char*)d_ws;
    size_t o = 0;
    auto alloc = [&](size_t bytes) {
        void* p = wsb + o;
        o += (bytes + 255) & ~(size_t)255;
        return p;
    };
    float* deg_p = (float*)alloc((size_t)NC * NN * 4);  // fully overwritten
    int*   cnt_p = (int*)alloc((size_t)NC * NN * 4);    // fully overwritten
    int*   cnt   = (int*)alloc(NN * 4);
    int*   cbase = (int*)alloc((size_t)NC * NN * 4);    // cbase[0..NN) == row_ptr
    float* dinv  = (float*)alloc(NN * 4);
    int*   bsum  = (int*)alloc(256 * 4);
    int*   ctr   = (int*)alloc(256);
    uint2* csr8  = (uint2*)alloc((size_t)EE * 8);
    u16*   Zb16  = (u16*)alloc((size_t)NN * 64 * 2);
    u16*   Hx16  = (u16*)alloc((size_t)NN * 64 * 2);
    u16*   A0    = (u16*)alloc((size_t)NN * 160 * 2);
    u16*   A1    = (u16*)alloc((size_t)NN * 160 * 2);
    u16*   A2    = (u16*)alloc((size_t)NN * 160 * 2);
    u16*   A3    = (u16*)alloc((size_t)NN * 192 * 2);
    u16*   Wp    = (u16*)alloc(15 * 12 * 512 * 2);
    u16*   W3p   = (u16*)alloc(6 * 4 * 512 * 2);

    float* outF = (float*)d_out;               // [B,128]
    float* outH = outF + (size_t)BB * 128;     // [N,64]

    const int BLK = 256;
    const int gPull160 = (NN + 31) / 32;  // 320 thr, 10 thr/row -> 32 rows/blk
    const int gPull64 = (NN + 63) / 64;   // 256 thr, 4 thr/row -> 64 rows/blk
    const int gTail = (BB * 64 + BLK - 1) / BLK;  // 250
    int* row_ptr = cbase;  // chunk-0 bases == row starts

    // 1. histograms (LDS-only atomics), resets barrier ctr
    k_hist<<<NR * NC, 512, 0, stream>>>(src, dst, ew, deg_p, cnt_p, ctr);

    // 2. build A0 + pack folded weights (no LDS, full occupancy)
    k_build<<<BUILDBLKS + PACKBLKS, 512, 0, stream>>>(
        z, x, ph, A0, Wxz, Wxr, Wxh, Whz, Whr, Whh, Wp, W3p);

    // 3. scan (barrier isolated): row_ptr/cbase/dinv
    k_scan<<<NB, 256, 0, stream>>>(cnt_p, deg_p, cnt, cbase, dinv, bsum, ctr);

    // 4. scatter CSR records via LDS ranks (no global atomics)
    k_scatter_rank<<<NR * NC, 512, 0, stream>>>(src, dst, ew, dinv, cbase, csr8);

    // 5. Chebyshev bases: A1 = -S(A0); A2 = -S(A1)  (T2 folded into packed weights)
    k_pull<160, 320, 160, 160><<<gPull160, 320, 0, stream>>>(A0, A1, csr8, row_ptr, cnt);
    k_pull<160, 320, 160, 160><<<gPull160, 320, 0, stream>>>(A1, A2, csr8, row_ptr, cnt);

    // 6. gates GEMM -> Zb16, Hx16, A3 slice 0 (hr)
    k_gates_mfma<<<FINBLKS, BLK, 0, stream>>>(A0, A1, A2, Wp, bxz, bhz, bxr, bhr, bxh,
                                              Zb16, Hx16, A3);

    // 7. Chebyshev basis for hr (within A3, stride 192)
    k_pull<64, 256, 192, 192><<<gPull64, 256, 0, stream>>>(A3, A3 + 64, csr8, row_ptr, cnt);
    k_pull<64, 256, 192, 192><<<gPull64, 256, 0, stream>>>(A3 + 64, A3 + 128, csr8, row_ptr, cnt);

    // 8. candidate GEMM + GRU blend -> h out; extra blocks do batch tail -> fused out
    k_final_tail<<<FINBLKS + gTail, BLK, 0, stream>>>(A3, W3p, bhh, Hx16, Zb16, A0, outH,
                                                      z, batch, u, Wg, bg, outF);
}

// Round 11
// 431.094 us; speedup vs baseline: 1.0631x; 1.0421x over previous
//
#include <hip/hip_runtime.h>

#define NN 50000
#define EE 800000
#define BB 1000
#define NB 196      // scan blocks (barrier participants)
#define NR 5        // node ranges for LDS histogram
#define RS 10496    // range size, NR*RS = 52480 >= NN
#define NC 32       // edge chunks / partial copies
#define CHUNK 25000 // EE/NC

#define BUILDBLKS 15625  // NN*160/512
#define PACKBLKS 204     // (15*12*512 + 6*4*512)/512
#define FINBLKS 782      // ceil(3125 waves / 4)

typedef unsigned short u16;
typedef __attribute__((ext_vector_type(8))) short bf16x8;
typedef __attribute__((ext_vector_type(4))) float f32x4;

static __device__ __forceinline__ u16 f2b(float f) {
    union { float f; unsigned u; } v;
    v.f = f;
    unsigned r = v.u + 0x7fffu + ((v.u >> 16) & 1u);
    return (u16)(r >> 16);
}

static __device__ __forceinline__ float b2f(short s) {
    union { unsigned u; float f; } c;
    c.u = ((unsigned)(u16)s) << 16;
    return c.f;
}

// ---------------- histogram: deg(src) f32 + cnt(dst) packed u16 + edge ranks ----------------
__global__ __launch_bounds__(512) void k_hist(
    const int* __restrict__ src, const int* __restrict__ dst,
    const float* __restrict__ ew, float* __restrict__ deg_p,
    int* __restrict__ cnt_p, int* __restrict__ rank, int* __restrict__ ctr) {
    __shared__ float sdeg[RS];
    __shared__ unsigned scnt2[RS / 2];
    if (blockIdx.x == 0 && threadIdx.x == 0) atomicExch(ctr, 0);  // for k_scan barrier
    int r = blockIdx.x % NR;
    int c = blockIdx.x / NR;
    int base = r * RS;
    for (int i = threadIdx.x; i < RS; i += 512) sdeg[i] = 0.f;
    for (int i = threadIdx.x; i < RS / 2; i += 512) scnt2[i] = 0u;
    __syncthreads();
    int e0 = c * CHUNK;
    for (int j = threadIdx.x; j < CHUNK; j += 512) {
        int e = e0 + j;
        int s = src[e], d = dst[e];
        int sl = s - base, dl = d - base;
        if ((unsigned)sl < RS) atomicAdd(&sdeg[sl], ew[e]);
        if ((unsigned)dl < RS) {
            unsigned old = atomicAdd(&scnt2[dl >> 1], (dl & 1) ? 65536u : 1u);
            rank[e] = (int)((old >> ((dl & 1) * 16)) & 0xffffu);
        }
    }
    __syncthreads();
    int lim = (NN - base < RS) ? (NN - base) : RS;
    for (int i = threadIdx.x; i < lim; i += 512) {
        deg_p[(size_t)c * NN + base + i] = sdeg[i];
        cnt_p[(size_t)c * NN + base + i] = (int)((scnt2[i >> 1] >> ((i & 1) * 16)) & 0xffffu);
    }
}

// ---------------- build A0 + pack weights (with Chebyshev folding) ----------------
// A-level k-layout per level: [x-part(96) | h-part(64)]; levels in A0/A1/A2.
// Folding: lvl0 -> W0 - W2, lvl1 -> W1, lvl2 -> 2*W2 (pull-2 computes U2 = -S(T1)).
__global__ __launch_bounds__(512) void k_build(
    const float* __restrict__ z, const float* __restrict__ x,
    const float* __restrict__ ph, u16* __restrict__ A0,
    const float* __restrict__ Wxz, const float* __restrict__ Wxr,
    const float* __restrict__ Wxh, const float* __restrict__ Whz,
    const float* __restrict__ Whr, const float* __restrict__ Whh,
    u16* __restrict__ Wp, u16* __restrict__ W3p) {
    int bid = blockIdx.x;
    if (bid < BUILDBLKS) {
        int i = bid * 512 + threadIdx.x;  // over NN*160 exactly
        int n = i / 160, c = i - n * 160;
        float v;
        if (c < 64) v = z[n * 64 + c];
        else if (c < 96) v = x[n * 32 + (c - 64)];
        else v = ph[n * 64 + (c - 96)];
        A0[(size_t)n * 160 + c] = f2b(v);
        return;
    }
    int idx = (bid - BUILDBLKS) * 512 + threadIdx.x;
    if (idx < 15 * 12 * 512) {
        int j = idx & 7, l = (idx >> 3) & 63;
        int ct = (idx >> 9) % 12, s = (idx >> 9) / 12;
        int k = 32 * s + (l >> 4) * 8 + j;
        int g = ct >> 2;
        int c = 16 * (ct & 3) + (l & 15);
        int lvl = k / 160, kk = k - lvl * 160;
        float val;
        if (kk < 96) {
            const float* W = (g == 0) ? Wxz : ((g == 1) ? Wxr : Wxh);
            if (lvl == 0)      val = W[kk * 64 + c] - W[(192 + kk) * 64 + c];
            else if (lvl == 1) val = W[(96 + kk) * 64 + c];
            else               val = 2.f * W[(192 + kk) * 64 + c];
        } else if (g == 2) {
            val = 0.f;
        } else {
            const float* W = (g == 0) ? Whz : Whr;
            int kh = kk - 96;
            if (lvl == 0)      val = W[kh * 64 + c] - W[(128 + kh) * 64 + c];
            else if (lvl == 1) val = W[(64 + kh) * 64 + c];
            else               val = 2.f * W[(128 + kh) * 64 + c];
        }
        Wp[idx] = f2b(val);
    } else {
        int i2 = idx - 15 * 12 * 512;
        int j = i2 & 7, l = (i2 >> 3) & 63;
        int ct = (i2 >> 9) & 3, s = i2 >> 11;
        int k = 32 * s + (l >> 4) * 8 + j;
        int ki = k >> 6, kr = k & 63;
        int c = 16 * ct + (l & 15);
        float val;
        if (ki == 0)      val = Whh[kr * 64 + c] - Whh[(128 + kr) * 64 + c];
        else if (ki == 1) val = Whh[(64 + kr) * 64 + c];
        else              val = 2.f * Whh[(128 + kr) * 64 + c];
        W3p[i2] = f2b(val);
    }
}

// ---------------- scan: reduce partials + prefix via grid barrier -> cbase/dinv ----------------
// No register array held across the barrier (round-10 spill); cnt_p re-read L2-warm.
__global__ __launch_bounds__(256) void k_scan(
    const int* __restrict__ cnt_p, const float* __restrict__ deg_p,
    int* __restrict__ cnt, int* __restrict__ cbase, float* __restrict__ dinv,
    int* __restrict__ bsum, int* __restrict__ ctr) {
    __shared__ int s[256];
    int b = blockIdx.x;
    int i = b * 256 + threadIdx.x;
    int v = 0;
    float d = 0.f;
    if (i < NN) {
#pragma unroll
        for (int p = 0; p < NC; p++) {
            v += cnt_p[(size_t)p * NN + i];
            d += deg_p[(size_t)p * NN + i];
        }
        cnt[i] = v;
        dinv[i] = d > 0.f ? rsqrtf(d) : 0.f;
    }
    s[threadIdx.x] = v;
    __syncthreads();
    for (int off = 1; off < 256; off <<= 1) {
        int t = (threadIdx.x >= off) ? s[threadIdx.x - off] : 0;
        __syncthreads();
        s[threadIdx.x] += t;
        __syncthreads();
    }
    int incl = s[threadIdx.x];
    if (threadIdx.x == 255) atomicExch(&bsum[b], s[255]);
    __threadfence();
    if (threadIdx.x == 0) {
        atomicAdd(ctr, 1);
        while (atomicAdd(ctr, 0) < NB) __builtin_amdgcn_s_sleep(8);
    }
    __syncthreads();
    __threadfence();
    int pv = (threadIdx.x < b) ? atomicAdd(&bsum[threadIdx.x], 0) : 0;
    s[threadIdx.x] = pv;
    __syncthreads();
    for (int off = 128; off > 0; off >>= 1) {
        if (threadIdx.x < off) s[threadIdx.x] += s[threadIdx.x + off];
        __syncthreads();
    }
    int prefix = s[0];
    if (i < NN) {
        int run = prefix + incl - v;  // row_ptr[i]
#pragma unroll
        for (int c = 0; c < NC; c++) {
            cbase[(size_t)c * NN + i] = run;
            run += cnt_p[(size_t)c * NN + i];  // L2-warm re-read (no spill)
        }
    }
}

// ---------------- scatter: single streaming pass, pos = cbase[chunk][dst] + rank[e] ----------------
__global__ void k_scatter(const int* __restrict__ src, const int* __restrict__ dst,
                          const float* __restrict__ ew, const float* __restrict__ dinv,
                          const int* __restrict__ cbase, const int* __restrict__ rank,
                          uint2* __restrict__ csr8) {
    int e = blockIdx.x * 256 + threadIdx.x;
    if (e >= EE) return;
    int c = e / CHUNK;
    int d = dst[e], s = src[e];
    int pos = cbase[(size_t)c * NN + d] + rank[e];
    float w = dinv[s] * ew[e] * dinv[d];
    csr8[pos] = make_uint2((unsigned)s, __float_as_uint(w));
}

// ---------------- bf16 pull propagation: out[r] = -sum w*in[src], 16 ch/thread ----------------
template <int C, int BS, int INS, int OUTS>
__global__ __launch_bounds__(BS) void k_pull(
    const u16* __restrict__ in, u16* __restrict__ out,
    const uint2* __restrict__ csr8, const int* __restrict__ row_ptr,
    const int* __restrict__ cnt) {
    constexpr int TPR = C / 16;
    int tid = blockIdx.x * BS + threadIdx.x;
    int r = tid / TPR;
    int c16 = (tid - r * TPR) * 16;
    if (r >= NN) return;
    int s0 = row_ptr[r], n = cnt[r];
    float acc[16];
#pragma unroll
    for (int k = 0; k < 16; k++) acc[k] = 0.f;
    const u16* inp = in + c16;
    uint2 e = (n > 0) ? csr8[s0] : make_uint2(0u, 0u);
    for (int j = 0; j < n; j++) {
        uint2 ec = e;
        if (j + 1 < n) e = csr8[s0 + j + 1];
        float w = __uint_as_float(ec.y);
        const u16* p = inp + (size_t)ec.x * INS;
        bf16x8 v0 = *(const bf16x8*)(p);
        bf16x8 v1 = *(const bf16x8*)(p + 8);
#pragma unroll
        for (int k = 0; k < 8; k++) {
            acc[k] += w * b2f(v0[k]);
            acc[8 + k] += w * b2f(v1[k]);
        }
    }
    bf16x8 p0, p1;
#pragma unroll
    for (int k = 0; k < 8; k++) {
        p0[k] = (short)f2b(-acc[k]);
        p1[k] = (short)f2b(-acc[8 + k]);
    }
    u16* op = out + (size_t)r * OUTS + c16;
    *(bf16x8*)(op) = p0;
    *(bf16x8*)(op + 8) = p1;
}

// ---------------- gates GEMM (MFMA): A0|A1|A2 x Wp[480,192] -> Zb16, Hx16, A3 ----------------
__global__ __launch_bounds__(256) void k_gates_mfma(
    const u16* __restrict__ A0, const u16* __restrict__ A1, const u16* __restrict__ A2,
    const u16* __restrict__ Wp,
    const float* __restrict__ bxz, const float* __restrict__ bhz,
    const float* __restrict__ bxr, const float* __restrict__ bhr,
    const float* __restrict__ bxh,
    u16* __restrict__ Zb16, u16* __restrict__ Hx16, u16* __restrict__ A3) {
    int wv = (blockIdx.x * 256 + threadIdx.x) >> 6;
    int lane = threadIdx.x & 63;
    int r0 = wv * 16;
    if (r0 >= NN) return;
    int q = lane >> 4, j0 = lane & 15;

    f32x4 acc[12];
#pragma unroll
    for (int i = 0; i < 12; i++) acc[i] = (f32x4){0.f, 0.f, 0.f, 0.f};

    size_t rofs = (size_t)(r0 + j0) * 160 + q * 8;
    const u16* arow[3] = {A0 + rofs, A1 + rofs, A2 + rofs};
#pragma unroll
    for (int s = 0; s < 15; s++) {
        bf16x8 a = *(const bf16x8*)(arow[s / 5] + 32 * (s % 5));
        const u16* bp = Wp + (size_t)(s * 12) * 512 + lane * 8;
#pragma unroll
        for (int ct = 0; ct < 12; ct++) {
            bf16x8 b = *(const bf16x8*)(bp + ct * 512);
            acc[ct] = __builtin_amdgcn_mfma_f32_16x16x32_bf16(a, b, acc[ct], 0, 0, 0);
        }
    }

#pragma unroll
    for (int ct = 0; ct < 4; ct++) {
        int j = 16 * ct + j0;
        float bz = bxz[j] + bhz[j];
        float br = bxr[j] + bhr[j];
        float bh = bxh[j];
#pragma unroll
        for (int reg = 0; reg < 4; reg++) {
            int r = r0 + q * 4 + reg;
            size_t i = (size_t)r * 64 + j;
            float zp = acc[ct][reg] + bz;
            float rp = acc[ct + 4][reg] + br;
            float hp = acc[ct + 8][reg] + bh;
            float zv = 1.f / (1.f + expf(-zp));
            float rv = 1.f / (1.f + expf(-rp));
            float phv = b2f((short)A0[(size_t)r * 160 + 96 + j]);
            Zb16[i] = f2b(zv);
            Hx16[i] = f2b(hp);
            A3[(size_t)r * 192 + j] = f2b(rv * phv);
        }
    }
}

// ---------------- final GEMM + GRU blend, fused with batch tail ----------------
__global__ __launch_bounds__(256) void k_final_tail(
    const u16* __restrict__ A3, const u16* __restrict__ W3p,
    const float* __restrict__ bhh, const u16* __restrict__ Hx16,
    const u16* __restrict__ Zb16, const u16* __restrict__ A0,
    float* __restrict__ outh,
    const float* __restrict__ z, const int* __restrict__ batch,
    const float* __restrict__ u, const float* __restrict__ Wg,
    const float* __restrict__ bg, float* __restrict__ outF) {
    if (blockIdx.x >= FINBLKS) {
        int b = ((blockIdx.x - FINBLKS) * 256 + threadIdx.x) >> 6;
        int lane = threadIdx.x & 63;
        if (b >= BB) return;
        int lo = 0, hi = NN;
        while (lo < hi) {
            int m = (lo + hi) >> 1;
            if (batch[m] < b) lo = m + 1; else hi = m;
        }
        int start = lo;
        hi = NN;
        while (lo < hi) {
            int m = (lo + hi) >> 1;
            if (batch[m] < b + 1) lo = m + 1; else hi = m;
        }
        int end = lo;
        float acc = 0.f;
        for (int n = start; n < end; n++) acc += z[(size_t)n * 64 + lane];
        float g = bg[lane];
        const float* ur = u + (size_t)b * 64;
        for (int k = 0; k < 64; k++) g += ur[k] * Wg[k * 64 + lane];
        g = fmaxf(g, 0.f);
        outF[(size_t)b * 128 + lane] = acc;
        outF[(size_t)b * 128 + 64 + lane] = g;
        return;
    }
    int wv = (blockIdx.x * 256 + threadIdx.x) >> 6;
    int lane = threadIdx.x & 63;
    int r0 = wv * 16;
    if (r0 >= NN) return;
    int q = lane >> 4, j0 = lane & 15;

    f32x4 acc[4];
#pragma unroll
    for (int i = 0; i < 4; i++) acc[i] = (f32x4){0.f, 0.f, 0.f, 0.f};

    const u16* arow = A3 + (size_t)(r0 + j0) * 192 + q * 8;
#pragma unroll
    for (int s = 0; s < 6; s++) {
        bf16x8 a = *(const bf16x8*)(arow + 32 * s);
        const u16* bp = W3p + (size_t)(s * 4) * 512 + lane * 8;
#pragma unroll
        for (int ct = 0; ct < 4; ct++) {
            bf16x8 b = *(const bf16x8*)(bp + ct * 512);
            acc[ct] = __builtin_amdgcn_mfma_f32_16x16x32_bf16(a, b, acc[ct], 0, 0, 0);
        }
    }

#pragma unroll
    for (int ct = 0; ct < 4; ct++) {
        int j = 16 * ct + j0;
        float bh = bhh[j];
#pragma unroll
        for (int reg = 0; reg < 4; reg++) {
            int r = r0 + q * 4 + reg;
            size_t i = (size_t)r * 64 + j;
            float ht = tanhf(b2f((short)Hx16[i]) + acc[ct][reg] + bh);
            float zv = b2f((short)Zb16[i]);
            float phv = b2f((short)A0[(size_t)r * 160 + 96 + j]);
            outh[i] = zv * phv + (1.f - zv) * ht;
        }
    }
}

extern "C" void kernel_launch(void* const* d_in, const int* in_sizes, int n_in,
                              void* d_out, int out_size, void* d_ws, size_t ws_size,
                              hipStream_t stream) {
    const float* x  = (const float*)d_in[0];
    const float* u  = (const float*)d_in[1];
    const float* z  = (const float*)d_in[2];
    const int*   ei = (const int*)d_in[3];
    const float* ew = (const float*)d_in[4];
    const int* batch = (const int*)d_in[5];
    const float* ph = (const float*)d_in[7];
    const float *Wxz = (const float*)d_in[8],  *bxz = (const float*)d_in[9];
    const float *Whz = (const float*)d_in[10], *bhz = (const float*)d_in[11];
    const float *Wxr = (const float*)d_in[12], *bxr = (const float*)d_in[13];
    const float *Whr = (const float*)d_in[14], *bhr = (const float*)d_in[15];
    const float *Wxh = (const float*)d_in[16], *bxh = (const float*)d_in[17];
    const float *Whh = (const float*)d_in[18], *bhh = (const float*)d_in[19];
    const float *Wg  = (const float*)d_in[20], *bg  = (const float*)d_in[21];
    const int* src = ei;
    const int* dst = ei + EE;

    char* wsb = (char*)d_ws;
    size_t o = 0;
    auto alloc = [&](size_t bytes) {
        void* p = wsb + o;
        o += (bytes + 255) & ~(size_t)255;
        return p;
    };
    float* deg_p = (float*)alloc((size_t)NC * NN * 4);  // fully overwritten
    int*   cnt_p = (int*)alloc((size_t)NC * NN * 4);    // fully overwritten
    int*   cnt   = (int*)alloc(NN * 4);
    int*   cbase = (int*)alloc((size_t)NC * NN * 4);    // cbase[0..NN) == row_ptr
    int*   rank  = (int*)alloc((size_t)EE * 4);
    float* dinv  = (float*)alloc(NN * 4);
    int*   bsum  = (int*)alloc(256 * 4);
    int*   ctr   = (int*)alloc(256);
    uint2* csr8  = (uint2*)alloc((size_t)EE * 8);
    u16*   Zb16  = (u16*)alloc((size_t)NN * 64 * 2);
    u16*   Hx16  = (u16*)alloc((size_t)NN * 64 * 2);
    u16*   A0    = (u16*)alloc((size_t)NN * 160 * 2);
    u16*   A1    = (u16*)alloc((size_t)NN * 160 * 2);
    u16*   A2    = (u16*)alloc((size_t)NN * 160 * 2);
    u16*   A3    = (u16*)alloc((size_t)NN * 192 * 2);
    u16*   Wp    = (u16*)alloc(15 * 12 * 512 * 2);
    u16*   W3p   = (u16*)alloc(6 * 4 * 512 * 2);

    float* outF = (float*)d_out;               // [B,128]
    float* outH = outF + (size_t)BB * 128;     // [N,64]

    const int BLK = 256;
    const int gE = (EE + BLK - 1) / BLK;
    const int gPull160 = (NN + 31) / 32;  // 320 thr, 10 thr/row -> 32 rows/blk
    const int gPull64 = (NN + 63) / 64;   // 256 thr, 4 thr/row -> 64 rows/blk
    const int gTail = (BB * 64 + BLK - 1) / BLK;  // 250
    int* row_ptr = cbase;  // chunk-0 bases == row starts

    // 1. histograms (LDS-only atomics) + edge ranks; resets barrier ctr
    k_hist<<<NR * NC, 512, 0, stream>>>(src, dst, ew, deg_p, cnt_p, rank, ctr);

    // 2. build A0 + pack folded weights (no LDS, full occupancy)
    k_build<<<BUILDBLKS + PACKBLKS, 512, 0, stream>>>(
        z, x, ph, A0, Wxz, Wxr, Wxh, Whz, Whr, Whh, Wp, W3p);

    // 3. scan (barrier isolated, spill-free): row_ptr/cbase/dinv
    k_scan<<<NB, 256, 0, stream>>>(cnt_p, deg_p, cnt, cbase, dinv, bsum, ctr);

    // 4. scatter CSR records: one streaming pass, no atomics, no LDS
    k_scatter<<<gE, BLK, 0, stream>>>(src, dst, ew, dinv, cbase, rank, csr8);

    // 5. Chebyshev bases: A1 = -S(A0); A2 = -S(A1)  (T2 folded into packed weights)
    k_pull<160, 320, 160, 160><<<gPull160, 320, 0, stream>>>(A0, A1, csr8, row_ptr, cnt);
    k_pull<160, 320, 160, 160><<<gPull160, 320, 0, stream>>>(A1, A2, csr8, row_ptr, cnt);

    // 6. gates GEMM -> Zb16, Hx16, A3 slice 0 (hr)
    k_gates_mfma<<<FINBLKS, BLK, 0, stream>>>(A0, A1, A2, Wp, bxz, bhz, bxr, bhr, bxh,
                                              Zb16, Hx16, A3);

    // 7. Chebyshev basis for hr (within A3, stride 192)
    k_pull<64, 256, 192, 192><<<gPull64, 256, 0, stream>>>(A3, A3 + 64, csr8, row_ptr, cnt);
    k_pull<64, 256, 192, 192><<<gPull64, 256, 0, stream>>>(A3 + 64, A3 + 128, csr8, row_ptr, cnt);

    // 8. candidate GEMM + GRU blend -> h out; extra blocks do batch tail -> fused out
    k_final_tail<<<FINBLKS + gTail, BLK, 0, stream>>>(A3, W3p, bhh, Hx16, Zb16, A0, outH,
                                                      z, batch, u, Wg, bg, outF);
}